// Round 2
// baseline (484.907 us; speedup 1.0000x reference)
//
#include <hip/hip_runtime.h>

// V: (1, 80, 96, 112, 16) f32  ->  out: (1, 160, 192, 224, 16) f32
// Separable 2x linear upsample, edge clamp. even = copy, odd = avg(i, i+1).
//
// R2 restructure: block = (h0, d-strip of KD=10 slices), 896 threads.
// Per iteration the block emits the output row-quad {2d,2d+1}x{2h0,2h0+1};
// rows (d+1,*) are loaded as C/D and ROTATED into A/B for the next iteration,
// so steady-state is 4 load instrs : 4 store instrs (was 8:4 one-shot) and
// read traffic halves. Waves are persistent (10 iters) so stores of iter i
// overlap the outstanding loads of iter i; r00/r01 need only A/B and are
// computed+stored BEFORE the C/D vmcnt wait.
//
// XCD chunking: grid = 768 = 8 strips x 96 h, strip = bid & 7. Hardware
// round-robins bid%8 across the 8 XCDs, so each XCD owns one full d-strip
// and sweeps h ascending -> the h+1 row (B/D) is re-read by block h+1 on the
// SAME XCD's L2 (default mapping put h-neighbors on different XCDs, forcing
// a 2x HBM re-fetch of the entire input).
//
// Reference grouping preserved exactly (absmax must stay 0):
//   r00 = avg(A0,A1)                       r01 = avg(avg(A0,B0), avg(A1,B1))
//   r10 = avg(avg(A0,C0), avg(A1,C1))      r11 = avg(avg(ac0,bd0), avg(ac1,bd1))
// even-w lanes use a duplicated second index (avg(x,x)==x exactly).
// Output stays non-temporal (write-once stream).

#define DV 80
#define HV 96
#define WV 112
#define KD 10                    // d-slices per strip (80 / 8 XCD-strips)
#define ROW4 (WV * 4)            // 448 float4 per input row
#define OROW4 (2 * WV * 4)       // 896 float4 per output row

typedef float v4f __attribute__((ext_vector_type(4)));

__device__ __forceinline__ float4 avg4(float4 x, float4 y) {
    return make_float4(0.5f * (x.x + y.x), 0.5f * (x.y + y.y),
                       0.5f * (x.z + y.z), 0.5f * (x.w + y.w));
}

__device__ __forceinline__ void store_nt(float4* p, float4 v) {
    __builtin_nontemporal_store(*reinterpret_cast<const v4f*>(&v),
                                reinterpret_cast<v4f*>(p));
}

__global__ __launch_bounds__(896, 7) void UpsampleInterp_kernel(
        const float4* __restrict__ in, float4* __restrict__ out) {
    const int bid   = blockIdx.x;      // 0..767
    const int strip = bid & 7;         // XCD id under default %8 round-robin
    const int h0    = bid >> 3;        // 0..95
    const int d0s   = strip * KD;

    const int t  = threadIdx.x;        // 0..895
    const int c4 = t & 3;              // channel quad
    const int wo = t >> 2;             // 0..223
    const int wi = wo >> 1;            // 0..111
    const int wodd = wo & 1;
    const int wib  = (wi + 1 < WV) ? wi + 1 : WV - 1;
    const int i1   = wodd ? wib : wi;  // duplicate for even lanes

    const int h1 = (h0 + 1 < HV) ? h0 + 1 : HV - 1;   // block-uniform

    const int off0 = c4 + 4 * wi;
    const int off1 = c4 + 4 * i1;

    // prologue: rows at d = d0s
    const int rowA = (d0s * HV + h0) * ROW4;
    const int rowB = (d0s * HV + h1) * ROW4;
    float4 A0 = in[rowA + off0], A1 = in[rowA + off1];
    float4 B0 = in[rowB + off0], B1 = in[rowB + off1];

    int ob = ((2 * d0s) * (2 * HV) + (2 * h0)) * OROW4 + t;

#pragma unroll 1
    for (int i = 0; i < KD; ++i) {
        const int d  = d0s + i;
        const int d1 = (d + 1 < DV) ? d + 1 : DV - 1;   // clamps only at d=79
        const int rowC = (d1 * HV + h0) * ROW4;
        const int rowD = (d1 * HV + h1) * ROW4;
        const float4 C0 = in[rowC + off0], C1 = in[rowC + off1];
        const float4 D0 = in[rowD + off0], D1 = in[rowD + off1];

        // outputs needing only A/B — computed+stored before the C/D wait
        const float4 ab0 = avg4(A0, B0), ab1 = avg4(A1, B1);
        store_nt(&out[ob],         avg4(A0, A1));    // (2d,   2h0)
        store_nt(&out[ob + OROW4], avg4(ab0, ab1));  // (2d,   2h0+1)

        // outputs needing C/D
        const float4 ac0 = avg4(A0, C0), ac1 = avg4(A1, C1);
        const float4 bd0 = avg4(B0, D0), bd1 = avg4(B1, D1);
        store_nt(&out[ob + (2 * HV) * OROW4],         avg4(ac0, ac1));                  // (2d+1, 2h0)
        store_nt(&out[ob + (2 * HV) * OROW4 + OROW4], avg4(avg4(ac0, bd0), avg4(ac1, bd1))); // (2d+1, 2h0+1)

        // rotate: rows d+1 become rows d
        A0 = C0; A1 = C1; B0 = D0; B1 = D1;
        ob += 2 * (2 * HV) * OROW4;   // advance two output d-rows
    }
}

extern "C" void kernel_launch(void* const* d_in, const int* in_sizes, int n_in,
                              void* d_out, int out_size, void* d_ws, size_t ws_size,
                              hipStream_t stream) {
    const float4* in = (const float4*)d_in[0];
    float4* out = (float4*)d_out;
    UpsampleInterp_kernel<<<dim3(HV * (DV / KD)), 896, 0, stream>>>(in, out);
}

// Round 3
// 449.172 us; speedup vs baseline: 1.0796x; 1.0796x over previous
//
#include <hip/hip_runtime.h>

// V: (1, 80, 96, 112, 16) f32  ->  out: (1, 160, 192, 224, 16) f32
// Separable 2x linear upsample, edge clamp. even = copy, odd = avg(i, i+1).
//
// R3 = R1 shape (one-shot block per (d0,h0), 896 threads, nt stores) with the
// global-load path fixed: R1 issued 8 load instrs/thread at 50% lane density
// (even/odd lane pairs duplicated addresses). Now each block stages its 4
// input rows (A,B,C,D = 28 KB) into LDS with 2 perfectly dense load instrs
// per thread (1024 B/wave, 100% unique), then reads fragments via
// ds_read_b128 (duplicated lanes = same-address LDS broadcast, free).
//
// Reference grouping preserved exactly (absmax must stay 0):
//   out(2d,2h)     = avg(A0,A1)
//   out(2d,2h+1)   = avg(avg(A0,B0), avg(A1,B1))
//   out(2d+1,2h)   = avg(avg(A0,C0), avg(A1,C1))
//   out(2d+1,2h+1) = avg(avg(ac0,bd0), avg(ac1,bd1))
// even-w lanes use a duplicated second index (avg(x,x)==x exactly).
// Output rows stored non-temporally (write-once stream, R1 win kept).

#define DV 80
#define HV 96
#define WV 112
#define ROW4 (WV * 4)            // 448 float4 per input row
#define OROW4 (2 * WV * 4)       // 896 float4 per output row

typedef float v4f __attribute__((ext_vector_type(4)));

__device__ __forceinline__ float4 avg4(float4 x, float4 y) {
    return make_float4(0.5f * (x.x + y.x), 0.5f * (x.y + y.y),
                       0.5f * (x.z + y.z), 0.5f * (x.w + y.w));
}

__device__ __forceinline__ void store_nt(float4* p, float4 v) {
    __builtin_nontemporal_store(*reinterpret_cast<const v4f*>(&v),
                                reinterpret_cast<v4f*>(p));
}

__global__ __launch_bounds__(896) void UpsampleInterp_kernel(
        const float4* __restrict__ in, float4* __restrict__ out) {
    __shared__ float4 sm[4][ROW4];         // rows A,B,C,D

    const int h0 = blockIdx.x;             // 0..95
    const int d0 = blockIdx.y;             // 0..79
    const int t  = threadIdx.x;            // 0..895

    const int d1 = (d0 + 1 < DV) ? d0 + 1 : DV - 1;  // block-uniform
    const int h1 = (h0 + 1 < HV) ? h0 + 1 : HV - 1;  // block-uniform

    // ---- stage 4 rows = 1792 float4 with 2 dense loads per thread ----
    // t < 448: row A -> sm[0], row C -> sm[2];  t >= 448: B -> sm[1], D -> sm[3]
    {
        const int lo   = (t < ROW4);
        const int jt   = lo ? t : t - ROW4;
        const int rAB  = lo ? (d0 * HV + h0) : (d0 * HV + h1);
        const int rCD  = lo ? (d1 * HV + h0) : (d1 * HV + h1);
        const int bank = lo ? 0 : 1;
        sm[bank][jt]     = in[rAB * ROW4 + jt];
        sm[bank + 2][jt] = in[rCD * ROW4 + jt];
    }
    __syncthreads();

    // ---- per-thread fragment reads (LDS broadcasts for duplicate lanes) ----
    const int c4 = t & 3;                  // channel quad
    const int wo = t >> 2;                 // 0..223
    const int wi = wo >> 1;                // 0..111
    const int wodd = wo & 1;
    const int wib  = (wi + 1 < WV) ? wi + 1 : WV - 1;
    const int i1   = wodd ? wib : wi;      // duplicate for even lanes

    const int j0 = 4 * wi + c4;
    const int j1 = 4 * i1 + c4;

    const float4 A0 = sm[0][j0], A1 = sm[0][j1];
    const float4 B0 = sm[1][j0], B1 = sm[1][j1];
    const float4 C0 = sm[2][j0], C1 = sm[2][j1];
    const float4 D0 = sm[3][j0], D1 = sm[3][j1];

    const float4 ab0 = avg4(A0, B0), ab1 = avg4(A1, B1);
    const float4 ac0 = avg4(A0, C0), ac1 = avg4(A1, C1);
    const float4 bd0 = avg4(B0, D0), bd1 = avg4(B1, D1);

    const float4 r00 = avg4(A0, A1);
    const float4 r01 = avg4(ab0, ab1);
    const float4 r10 = avg4(ac0, ac1);
    const float4 r11 = avg4(avg4(ac0, bd0), avg4(ac1, bd1));

    // ---- 4 contiguous row stores, non-temporal ----
    const int ob = ((2 * d0) * (2 * HV) + (2 * h0)) * OROW4 + t;
    store_nt(&out[ob],                            r00);   // (2d0,   2h0)
    store_nt(&out[ob + OROW4],                    r01);   // (2d0,   2h0+1)
    store_nt(&out[ob + (2 * HV) * OROW4],         r10);   // (2d0+1, 2h0)
    store_nt(&out[ob + (2 * HV) * OROW4 + OROW4], r11);   // (2d0+1, 2h0+1)
}

extern "C" void kernel_launch(void* const* d_in, const int* in_sizes, int n_in,
                              void* d_out, int out_size, void* d_ws, size_t ws_size,
                              hipStream_t stream) {
    const float4* in = (const float4*)d_in[0];
    float4* out = (float4*)d_out;
    dim3 grid(HV, DV);  // (h0, d0) = (96, 80)
    UpsampleInterp_kernel<<<grid, 896, 0, stream>>>(in, out);
}